// Round 21
// baseline (331.302 us; speedup 1.0000x reference)
//
#include <hip/hip_runtime.h>
#include <math.h>

#define T_TOKENS 16384
#define HID      4096
#define NEXP     256
#define NGROUP   8
#define GSIZE    32
#define TOPKG    4
#define TOPK     8
#define RSCALE   2.5f

#define TAU   1.5e-5f    // expert-score margin (R13-validated)
#define TAUG  2.5e-5f    // group-score margin  (R13-validated)

// ---- split-K GEMM config (R9-validated) ----
#define BM     64
#define BK     32
#define SPLITK 4
#define KSPAN  (HID / SPLITK)    // 1024
#define NKS    (KSPAN / BK)      // 32 K-steps per block
#define NSG    (HID / BK)        // 128 global K-steps

// gemm LDS: A staging only, DOUBLE-BUFFERED (ushorts), frag-major (R9-validated):
//   elem(r,k) = (r>>4)*512 + ((k&31)>>3)*128 + (r&15)*8 + (k&7)
#define A_HI   0
#define A_LO   2048
#define A_BUF  4096              // ushorts per buffer (8 KB); x2 = 16 KB

// converted-weight limb size (ushorts): 128 steps x 8192
#define WQ_LIMB (NSG * 8192)

#define RT_TOK 16                // route tokens/block -> grid 1024, 4 blocks/CU

typedef __attribute__((ext_vector_type(8))) short bf16x8;
typedef __attribute__((ext_vector_type(4))) float f32x4;

__device__ __forceinline__ int stoffA(int r, int q) {
    return (r >> 4) * 512 + (q >> 1) * 128 + (r & 15) * 8 + (q & 1) * 4;
}
__device__ __forceinline__ int froffL(int lane) {
    return (lane >> 4) * 128 + (lane & 15) * 8;
}

// Split float4 into packed bf16 hi (RNE) and lo (RNE of exact residual).
__device__ __forceinline__ void split4(const float4 v, uint& h01, uint& h23,
                                       uint& l01, uint& l23) {
    const uint u0 = __float_as_uint(v.x) + 0x8000u;
    const uint u1 = __float_as_uint(v.y) + 0x8000u;
    const uint u2 = __float_as_uint(v.z) + 0x8000u;
    const uint u3 = __float_as_uint(v.w) + 0x8000u;
    h01 = __builtin_amdgcn_perm(u1, u0, 0x07060302u);
    h23 = __builtin_amdgcn_perm(u3, u2, 0x07060302u);
    const float f0 = v.x - __uint_as_float(u0 & 0xFFFF0000u);
    const float f1 = v.y - __uint_as_float(u1 & 0xFFFF0000u);
    const float f2 = v.z - __uint_as_float(u2 & 0xFFFF0000u);
    const float f3 = v.w - __uint_as_float(u3 & 0xFFFF0000u);
    l01 = __builtin_amdgcn_perm(__float_as_uint(f1) + 0x8000u,
                                __float_as_uint(f0) + 0x8000u, 0x07060302u);
    l23 = __builtin_amdgcn_perm(__float_as_uint(f3) + 0x8000u,
                                __float_as_uint(f2) + 0x8000u, 0x07060302u);
}

// ---- shared routing decision (identical in all paths; validated R5-R20) ----
template <class SC>
__device__ __forceinline__ bool route_core(SC sc, const float* __restrict__ bias,
                                           int* id, float* wv)
{
    float gs[NGROUP];
#pragma unroll
    for (int g = 0; g < NGROUP; ++g) {
        float m1 = -1e30f, m2 = -1e30f;
        for (int i = 0; i < GSIZE; ++i) {
            const int e = g * GSIZE + i;
            const float v = sc(e) + bias[e];
            if (v > m1)      { m2 = m1; m1 = v; }
            else if (v > m2) { m2 = v; }
        }
        gs[g] = m1 + m2;
    }

    unsigned gmask = 0;
    float g4 = -1e30f;
#pragma unroll
    for (int r = 0; r < TOPKG; ++r) {
        int bi = 0; float bv = -1e30f;
#pragma unroll
        for (int g = 0; g < NGROUP; ++g) {
            const bool taken = (gmask >> g) & 1;
            if (!taken && gs[g] > bv) { bv = gs[g]; bi = g; }
        }
        gmask |= 1u << bi;
        g4 = bv;
    }
    float g5 = -1e30f;
#pragma unroll
    for (int g = 0; g < NGROUP; ++g)
        if (!((gmask >> g) & 1) && gs[g] > g5) g5 = gs[g];

    float val[TOPK + 1]; int vid[TOPK + 1];
#pragma unroll
    for (int r = 0; r <= TOPK; ++r) { val[r] = -1e30f; vid[r] = 0; }
    for (int e = 0; e < NEXP; ++e) {
        const bool allowed = (gmask >> (e >> 5)) & 1;
        const float v = allowed ? (sc(e) + bias[e]) : 0.0f;
        if (v > val[TOPK]) {
#pragma unroll
            for (int p = TOPK; p >= 1; --p) {
                if (v > val[p - 1])  { val[p] = val[p - 1]; vid[p] = vid[p - 1]; }
                else if (v > val[p]) { val[p] = v;          vid[p] = e; }
            }
            if (v > val[0]) { val[0] = v; vid[0] = e; }
        }
    }

    bool tight = (g4 - g5 < TAUG);
#pragma unroll
    for (int i = 0; i < TOPK; ++i) tight |= (val[i] - val[i + 1] < TAU);

    float sum = 0.0f;
#pragma unroll
    for (int r = 0; r < TOPK; ++r) { id[r] = vid[r]; wv[r] = sc(vid[r]); sum += wv[r]; }
    const float inv = RSCALE / (sum + 1e-20f);
#pragma unroll
    for (int r = 0; r < TOPK; ++r) wv[r] *= inv;
    return tight;
}

// exact fp32 recompute + route for one token (cold fallback only)
__device__ void exact_token(const float* __restrict__ hs, const float* __restrict__ wt,
                            const float* __restrict__ bias, float* __restrict__ out, int t)
{
    float lg[NEXP];
    const float* hrow = hs + (size_t)t * HID;
    for (int e = 0; e < NEXP; ++e) {
        const float* wr = wt + (size_t)e * HID;
        float a = 0.0f;
        for (int k = 0; k < HID; k += 4) {
            const float4 x = *(const float4*)(hrow + k);
            const float4 b = *(const float4*)(wr + k);
            a = fmaf(x.x, b.x, a); a = fmaf(x.y, b.y, a);
            a = fmaf(x.z, b.z, a); a = fmaf(x.w, b.w, a);
        }
        lg[e] = 1.0f / (1.0f + expf(-a));
    }
    int id[TOPK]; float wv[TOPK];
    route_core([&](int e) { return lg[e]; }, bias, id, wv);
    for (int r = 0; r < TOPK; ++r) {
        out[(size_t)t * TOPK + r] = (float)id[r];
        out[(size_t)T_TOKENS * TOPK + (size_t)t * TOPK + r] = wv[r];
    }
}

// =============== one-shot weight conversion (R9-validated, unchanged) ===============
__global__ __launch_bounds__(256, 8)
void conv_weight(const float* __restrict__ wt, ushort* __restrict__ wq)
{
    const int g  = blockIdx.x * 256 + threadIdx.x;
    const int e  = g >> 9;
    const int kc = g & 511;
    const int sg  = kc >> 2;
    const int kch = kc & 3;

    const float4 v0 = *(const float4*)(wt + (size_t)e * HID + kc * 8);
    const float4 v1 = *(const float4*)(wt + (size_t)e * HID + kc * 8 + 4);
    uint h01, h23, l01, l23, h45, h67, l45, l67;
    split4(v0, h01, h23, l01, l23);
    split4(v1, h45, h67, l45, l67);

    const size_t idx = (size_t)sg * 8192 + (size_t)((e >> 4) * 512 + kch * 128 + (e & 15) * 8);
    uint4 hv; hv.x = h01; hv.y = h23; hv.z = h45; hv.w = h67;
    uint4 lv; lv.x = l01; lv.y = l23; lv.z = l45; lv.w = l67;
    *(uint4*)&wq[idx] = hv;
    *(uint4*)&wq[(size_t)WQ_LIMB + idx] = lv;
}

// =============== split-K GEMM v6: B direct (R20) + A double-buffer, 1 barrier/step ===============
// Writes to buf^1 in iter k race only with reads of buf^1 in iter k-1, which the
// iter-k-1 barrier orders; reads of buf^1 in iter k+1 see iter-k writes likewise.
// XCD-local swizzle (R14): b = g*32 + s*8 + x -> m = g*8 + x, sk = s.
__global__ __launch_bounds__(256, 4)
void router_gemm(const float* __restrict__ hs, const ushort* __restrict__ wq,
                 float* __restrict__ pw)
{
    __shared__ ushort u16[2 * A_BUF];    // 16 KB, A dbuf

    const int tid  = threadIdx.x;
    const int lane = tid & 63;
    const int w    = tid >> 6;
    const int b    = blockIdx.x;
    const int m    = (b >> 5) * 8 + (b & 7);
    const int sk   = (b >> 3) & 3;
    const int t0   = m * BM;
    const int kb0  = sk * KSPAN;
    const int r0   = tid >> 3;           // 0..31
    const int q    = tid & 7;

    const ushort* wq_hi = wq;
    const ushort* wq_lo = wq + WQ_LIMB;

    f32x4 acc[4][4];
#pragma unroll
    for (int i = 0; i < 4; ++i)
#pragma unroll
        for (int j = 0; j < 4; ++j) acc[i][j] = (f32x4)0.0f;

    // ---- prologue: stage A(0) into buf0; prefetch A(1) regs ----
    float4 ra[2];
    {
#pragma unroll
        for (int s = 0; s < 2; ++s) {
            const float4 v = *(const float4*)(hs + (size_t)(t0 + r0 + 32 * s) * HID + kb0 + q * 4);
            uint h01, h23, l01, l23;
            split4(v, h01, h23, l01, l23);
            const int eo = stoffA(r0 + 32 * s, q);
            uint2 hv; hv.x = h01; hv.y = h23;
            uint2 lv; lv.x = l01; lv.y = l23;
            *(uint2*)&u16[A_HI + eo] = hv;
            *(uint2*)&u16[A_LO + eo] = lv;
        }
#pragma unroll
        for (int s = 0; s < 2; ++s)
            ra[s] = *(const float4*)(hs + (size_t)(t0 + r0 + 32 * s) * HID + kb0 + BK + q * 4);
    }
    __syncthreads();   // buf0 visible

    int cur = 0;
    for (int ks = 0; ks < NKS; ++ks) {
        const int sg = sk * NKS + ks;
        ushort* bc = u16 + cur * A_BUF;
        ushort* bn = u16 + (cur ^ 1) * A_BUF;

        // ---- stage A(ks+1) into buf^1 (overlaps compute below) ----
        if (ks + 1 < NKS) {
#pragma unroll
            for (int s = 0; s < 2; ++s) {
                uint h01, h23, l01, l23;
                split4(ra[s], h01, h23, l01, l23);
                const int eo = stoffA(r0 + 32 * s, q);
                uint2 hv; hv.x = h01; hv.y = h23;
                uint2 lv; lv.x = l01; lv.y = l23;
                *(uint2*)&bn[A_HI + eo] = hv;
                *(uint2*)&bn[A_LO + eo] = lv;
            }
            if (ks + 2 < NKS) {
                const int kb = kb0 + (ks + 2) * BK;
#pragma unroll
                for (int s = 0; s < 2; ++s)
                    ra[s] = *(const float4*)(hs + (size_t)(t0 + r0 + 32 * s) * HID + kb + q * 4);
            }
        }

        // ---- B: direct per-lane frag loads from L2-resident wq (coalesced 16B) ----
        bf16x8 bh[4], bl[4];
        {
            const size_t bb = (size_t)sg * 8192 + (size_t)(w * 4) * 512 + (size_t)lane * 8;
#pragma unroll
            for (int c = 0; c < 4; ++c) {
                bh[c] = *(const bf16x8*)(wq_hi + bb + c * 512);
                bl[c] = *(const bf16x8*)(wq_lo + bb + c * 512);
            }
        }

        // ---- A frags from buf cur (linear b128, bank floor) + 48 MFMA/wave ----
        const int fo = froffL(lane);
        bf16x8 ah[4], al[4];
#pragma unroll
        for (int rt = 0; rt < 4; ++rt) {
            ah[rt] = *(const bf16x8*)&bc[A_HI + rt * 512 + fo];
            al[rt] = *(const bf16x8*)&bc[A_LO + rt * 512 + fo];
        }
#pragma unroll
        for (int c = 0; c < 4; ++c) {
#pragma unroll
            for (int rt = 0; rt < 4; ++rt) {
                acc[rt][c] = __builtin_amdgcn_mfma_f32_16x16x32_bf16(ah[rt], bh[c], acc[rt][c], 0, 0, 0);
                acc[rt][c] = __builtin_amdgcn_mfma_f32_16x16x32_bf16(ah[rt], bl[c], acc[rt][c], 0, 0, 0);
                acc[rt][c] = __builtin_amdgcn_mfma_f32_16x16x32_bf16(al[rt], bh[c], acc[rt][c], 0, 0, 0);
            }
        }

        __syncthreads();   // buf cur fully consumed AND buf^1 writes visible
        cur ^= 1;
    }

    // ---- store raw partial logits: pw[sk][token][expert] ----
#pragma unroll
    for (int rt = 0; rt < 4; ++rt)
#pragma unroll
        for (int c = 0; c < 4; ++c) {
            const int col  = w * 64 + c * 16 + (lane & 15);
            const int rowb = rt * 16 + (lane >> 4) * 4;
#pragma unroll
            for (int j = 0; j < 4; ++j)
                pw[((size_t)(sk * T_TOKENS) + t0 + rowb + j) * NEXP + col] = acc[rt][c][j];
        }
}

// =============== routing v2: 16 tokens/block, grid 1024 (4 blocks/CU) ===============
// block b_r -> m with m%8 == b_r%8 (same XCD as the gemm blocks that wrote pw[m])
__global__ __launch_bounds__(256, 4)
void router_route(const float* __restrict__ pw, const float* __restrict__ bias,
                  float* __restrict__ out,
                  unsigned* __restrict__ wcnt, unsigned* __restrict__ wlist,
                  unsigned cap)
{
    __shared__ float Lg[NEXP * RT_TOK];  // 16 KB
    const int tid  = threadIdx.x;
    const int b    = blockIdx.x;         // 1024
    const int x    = b & 7;
    const int rest = b >> 3;             // 0..127
    const int m    = (rest >> 2) * 8 + x;
    const int sub  = rest & 3;
    const int t0   = m * BM + sub * RT_TOK;

#pragma unroll
    for (int t = 0; t < RT_TOK; ++t) {
        float v = 0.0f;
#pragma unroll
        for (int s = 0; s < SPLITK; ++s)
            v += pw[((size_t)(s * T_TOKENS) + t0 + t) * NEXP + tid];
        Lg[tid * RT_TOK + ((t + tid) & (RT_TOK - 1))] = 1.0f / (1.0f + expf(-v));
    }
    __syncthreads();

    if (tid < RT_TOK) {
        const int t = t0 + tid;
        int id[TOPK]; float wv[TOPK];
        const bool tight = route_core(
            [&](int e) { return Lg[e * RT_TOK + ((tid + e) & (RT_TOK - 1))]; },
            bias, id, wv);

#pragma unroll
        for (int r = 0; r < TOPK; ++r) {
            out[(size_t)t * TOPK + r] = (float)id[r];
            out[(size_t)T_TOKENS * TOPK + (size_t)t * TOPK + r] = wv[r];
        }
        if (tight) {
            const unsigned pos = atomicAdd(wcnt, 1u);
            if (pos < cap) wlist[pos] = (unsigned)t;
        }
    }
}

// =============== cleanup v3 (R8-verbatim): one token per block, deep-issue ===============
__global__ __launch_bounds__(256, 4)
void router_exact(const float* __restrict__ hs, const float* __restrict__ wt,
                  const float* __restrict__ bias, float* __restrict__ out,
                  const unsigned* __restrict__ wcnt, const unsigned* __restrict__ wlist,
                  unsigned cap)
{
    __shared__ float hrow[HID];          // 16 KB
    __shared__ float lg[NEXP];           // 1 KB
    const unsigned count = min(*wcnt, cap);
    const int tid  = threadIdx.x;
    const int lane = tid & 63;
    const int w    = tid >> 6;

    for (unsigned b = blockIdx.x; b < count; b += gridDim.x) {
        __syncthreads();                 // guard hrow/lg reuse across passes
        const int t = (int)wlist[b];

#pragma unroll
        for (int i = 0; i < 4; ++i) {
            const int f4 = i * 256 + tid;
            *(float4*)&hrow[f4 * 4] = *(const float4*)(hs + (size_t)t * HID + f4 * 4);
        }
        __syncthreads();

        for (int g = 0; g < 16; ++g) {
            const int e0 = w * 64 + g * 4;
            float a[4] = {0.0f, 0.0f, 0.0f, 0.0f};
#pragma unroll 4
            for (int j = 0; j < 16; ++j) {
                const int f4 = j * 64 + lane;
                const float4 h = *(const float4*)&hrow[f4 * 4];
#pragma unroll
                for (int p = 0; p < 4; ++p) {
                    const float4 v = *(const float4*)(wt + (size_t)(e0 + p) * HID + f4 * 4);
                    a[p] = fmaf(h.x, v.x, a[p]); a[p] = fmaf(h.y, v.y, a[p]);
                    a[p] = fmaf(h.z, v.z, a[p]); a[p] = fmaf(h.w, v.w, a[p]);
                }
            }
#pragma unroll
            for (int p = 0; p < 4; ++p)
#pragma unroll
                for (int d = 1; d < 64; d <<= 1)
                    a[p] += __shfl_xor(a[p], d, 64);
            if (lane == 0) {
#pragma unroll
                for (int p = 0; p < 4; ++p)
                    lg[e0 + p] = 1.0f / (1.0f + expf(-a[p]));
            }
        }
        __syncthreads();

        if (tid == 0) {
            int id[TOPK]; float wv[TOPK];
            route_core([&](int e) { return lg[e]; }, bias, id, wv);
            for (int r = 0; r < TOPK; ++r) {
                out[(size_t)t * TOPK + r] = (float)id[r];
                out[(size_t)T_TOKENS * TOPK + (size_t)t * TOPK + r] = wv[r];
            }
        }
    }
}

// =============== fallback monolith (R5-validated, unchanged) ===============
__global__ __launch_bounds__(512, 1)
void router_mono(const float* __restrict__ hs, const float* __restrict__ wt,
                 const float* __restrict__ bias, float* __restrict__ out,
                 unsigned* __restrict__ wcnt, unsigned* __restrict__ wlist, unsigned cap)
{
    __shared__ float smem[16384];
    ushort* u16 = (ushort*)smem;
    float*  Lg  = smem;

    const int tid  = threadIdx.x;
    const int lane = tid & 63;
    const int w    = tid >> 6;
    const int t0   = blockIdx.x * 64;
    const int ar   = tid >> 3;
    const int aq   = tid & 7;

    f32x4 acc[4][2];
#pragma unroll
    for (int i = 0; i < 4; ++i)
#pragma unroll
        for (int j = 0; j < 2; ++j) acc[i][j] = (f32x4)0.0f;

    float4 ra, rb[4];
    ra = *(const float4*)(hs + (size_t)(t0 + ar) * HID + aq * 4);
#pragma unroll
    for (int s = 0; s < 4; ++s)
        rb[s] = *(const float4*)(wt + (size_t)(ar + s * 64) * HID + aq * 4);

    for (int ks = 0; ks < HID / BK; ++ks) {
        __syncthreads();
        {
            uint h01, h23, l01, l23;
            split4(ra, h01, h23, l01, l23);
            const int eo = stoffA(ar, aq);
            uint2 hv; hv.x = h01; hv.y = h23;
            uint2 lv; lv.x = l01; lv.y = l23;
            *(uint2*)&u16[0 + eo] = hv;
            *(uint2*)&u16[2048 + eo] = lv;
        }
#pragma unroll
        for (int s = 0; s < 4; ++s) {
            const int e = ar + s * 64;
            uint h01, h23, l01, l23;
            split4(rb[s], h01, h23, l01, l23);
            const int eo = stoffA(e, aq);
            uint2 hv; hv.x = h01; hv.y = h23;
            uint2 lv; lv.x = l01; lv.y = l23;
            *(uint2*)&u16[4096 + eo] = hv;
            *(uint2*)&u16[12288 + eo] = lv;
        }
        __syncthreads();
        if (ks + 1 < HID / BK) {
            const int k0 = (ks + 1) * BK;
            ra = *(const float4*)(hs + (size_t)(t0 + ar) * HID + k0 + aq * 4);
#pragma unroll
            for (int s = 0; s < 4; ++s)
                rb[s] = *(const float4*)(wt + (size_t)(ar + s * 64) * HID + k0 + aq * 4);
        }
        const int fo = froffL(lane);
        bf16x8 ah[4], al[4];
#pragma unroll
        for (int rt = 0; rt < 4; ++rt) {
            ah[rt] = *(const bf16x8*)&u16[0 + rt * 512 + fo];
            al[rt] = *(const bf16x8*)&u16[2048 + rt * 512 + fo];
        }
#pragma unroll
        for (int c = 0; c < 2; ++c) {
            const int ct = w * 2 + c;
            const bf16x8 bh = *(const bf16x8*)&u16[4096 + ct * 512 + fo];
            const bf16x8 bl = *(const bf16x8*)&u16[12288 + ct * 512 + fo];
#pragma unroll
            for (int rt = 0; rt < 4; ++rt) {
                acc[rt][c] = __builtin_amdgcn_mfma_f32_16x16x32_bf16(ah[rt], bh, acc[rt][c], 0, 0, 0);
                acc[rt][c] = __builtin_amdgcn_mfma_f32_16x16x32_bf16(ah[rt], bl, acc[rt][c], 0, 0, 0);
                acc[rt][c] = __builtin_amdgcn_mfma_f32_16x16x32_bf16(al[rt], bh, acc[rt][c], 0, 0, 0);
            }
        }
    }
    __syncthreads();
#pragma unroll
    for (int rt = 0; rt < 4; ++rt)
#pragma unroll
        for (int c = 0; c < 2; ++c) {
            const int col  = w * 32 + c * 16 + (lane & 15);
            const int rowb = rt * 16 + (lane >> 4) * 4;
#pragma unroll
            for (int j = 0; j < 4; ++j) {
                const int row = rowb + j;
                Lg[col * 64 + ((row + col) & 63)] = 1.0f / (1.0f + expf(-acc[rt][c][j]));
            }
        }
    __syncthreads();

    if (tid < 64) {
        const int t = t0 + tid;
        int id[TOPK]; float wv[TOPK];
        const bool tight = route_core(
            [&](int e) { return Lg[e * 64 + ((tid + e) & 63)]; }, bias, id, wv);
#pragma unroll
        for (int r = 0; r < TOPK; ++r) {
            out[(size_t)t * TOPK + r] = (float)id[r];
            out[(size_t)T_TOKENS * TOPK + (size_t)t * TOPK + r] = wv[r];
        }
        if (tight) {
            bool queued = false;
            if (wcnt) {
                const unsigned pos = atomicAdd(wcnt, 1u);
                if (pos < cap) { wlist[pos] = (unsigned)t; queued = true; }
            }
            if (!queued) exact_token(hs, wt, bias, out, t);
        }
    }
}

extern "C" void kernel_launch(void* const* d_in, const int* in_sizes, int n_in,
                              void* d_out, int out_size, void* d_ws, size_t ws_size,
                              hipStream_t stream) {
    const float* hs   = (const float*)d_in[0];   // [16384, 4096] f32
    const float* wt   = (const float*)d_in[1];   // [256, 4096]   f32
    const float* bias = (const float*)d_in[2];   // [256]         f32
    float* out = (float*)d_out;
    (void)in_sizes; (void)n_in; (void)out_size;

    const size_t PW_BYTES = (size_t)SPLITK * T_TOKENS * NEXP * 4;   // 64 MB
    const size_t WQ_BYTES = (size_t)2 * WQ_LIMB * 2;                // 4 MB
    const size_t NEED = PW_BYTES + WQ_BYTES + 4 + (size_t)T_TOKENS * 4;

    if (ws_size >= NEED) {
        float*    pw    = (float*)d_ws;
        ushort*   wq    = (ushort*)((char*)d_ws + PW_BYTES);
        unsigned* wcnt  = (unsigned*)((char*)d_ws + PW_BYTES + WQ_BYTES);
        unsigned* wlist = wcnt + 1;
        hipMemsetAsync(wcnt, 0, sizeof(unsigned), stream);
        conv_weight<<<512, 256, 0, stream>>>(wt, wq);
        router_gemm<<<(T_TOKENS / BM) * SPLITK, 256, 0, stream>>>(hs, wq, pw);
        router_route<<<T_TOKENS / RT_TOK, 256, 0, stream>>>(pw, bias, out, wcnt, wlist,
                                                            (unsigned)T_TOKENS);
        router_exact<<<2048, 256, 0, stream>>>(hs, wt, bias, out, wcnt, wlist,
                                               (unsigned)T_TOKENS);
    } else if (ws_size >= 8) {
        unsigned cap = (unsigned)((ws_size - 4) / 4);
        if (cap > T_TOKENS) cap = T_TOKENS;
        unsigned* wcnt  = (unsigned*)d_ws;
        unsigned* wlist = wcnt + 1;
        hipMemsetAsync(d_ws, 0, sizeof(unsigned), stream);
        router_mono<<<T_TOKENS / 64, 512, 0, stream>>>(hs, wt, bias, out, wcnt, wlist, cap);
        router_exact<<<2048, 256, 0, stream>>>(hs, wt, bias, out, wcnt, wlist, cap);
    } else {
        router_mono<<<T_TOKENS / 64, 512, 0, stream>>>(hs, wt, bias, out,
                                                       nullptr, nullptr, 0u);
    }
}